// Round 6
// baseline (434.494 us; speedup 1.0000x reference)
//
#include <hip/hip_runtime.h>
#include <hip/hip_fp16.h>
#include <hip/hip_cooperative_groups.h>

namespace cg = cooperative_groups;

// GradientsLeastSquares — R6: fused cooperative kernel WITH error-checked
// fallback to the R4 3-kernel path. R5's absmax=812 (output never written)
// is consistent with hipLaunchCooperativeKernel failing synchronously and
// unchecked. If coop launch errors, we fall back deterministically in-call.

constexpr int N_NODES = 300000;
constexpr int DEG = 16;
constexpr float EPS_W = 1e-12f;
constexpr double EPS_A = 1e-8;

constexpr int NBLK = 1024;                 // 4 blocks/CU x 256 CUs
constexpr int TPB  = 256;
constexpr int GRP  = TPB / 16;             // 16 node-groups per block
constexpr int NPB  = (N_NODES + NBLK - 1) / NBLK;   // 293
constexpr int ITER = (NPB + GRP - 1) / GRP;         // 19

typedef float f32x4 __attribute__((ext_vector_type(4)));
typedef float f32x2 __attribute__((ext_vector_type(2)));

__device__ __forceinline__ float redux16(float v) {
    v += __shfl_xor(v, 1, 16);
    v += __shfl_xor(v, 2, 16);
    v += __shfl_xor(v, 4, 16);
    v += __shfl_xor(v, 8, 16);
    return v;
}

// ==================== FUSED COOPERATIVE KERNEL ====================

__global__ __launch_bounds__(TPB, 4) void lsq_fused(
    const float* __restrict__ coords,
    const float* __restrict__ u,
    const int*   __restrict__ indices,
    float4*      __restrict__ P1,
    float4*      __restrict__ G,
    float*       __restrict__ out)
{
    __shared__ float sM[ITER * GRP][6];    // per-node A^{-1}, 7.3 KB

    const int tid   = threadIdx.x;
    const int sub   = tid >> 4;
    const int lane  = tid & 15;
    const int nbase = blockIdx.x * NPB;

    // phase 0: pack P1[i] = {coords.xyz, u}
    for (int i = blockIdx.x * TPB + tid; i < N_NODES; i += NBLK * TPB) {
        P1[i] = make_float4(coords[3 * i], coords[3 * i + 1],
                            coords[3 * i + 2], u[i]);
    }
    cg::this_grid().sync();

    // phase 1: scalar gradient; per-edge state kept in registers
    int          idxr[ITER];
    unsigned int wxyr[ITER];   // half2 {wx, wy}
    float        wzr [ITER];   // wz f32

    #pragma unroll
    for (int t = 0; t < ITER; ++t) {
        const int local = t * GRP + sub;
        const int node  = nbase + local;
        const bool act  = (local < NPB) && (node < N_NODES);

        int j = 0;
        float dx = 0.f, dy = 0.f, dz = 0.f, dv = 0.f, w = 0.f;
        if (act) {
            float4 c = P1[node];
            j = __builtin_nontemporal_load(indices + node * DEG + lane);
            float4 p = P1[j];
            dx = p.x - c.x; dy = p.y - c.y; dz = p.z - c.z; dv = p.w - c.w;
            w = 1.0f / fmaxf(dx * dx + dy * dy + dz * dz, EPS_W);
        }
        float wx = w * dx, wy = w * dy, wz = w * dz;
        idxr[t] = j;
        union { __half2 h2; unsigned int ui; } pk;
        pk.h2 = __halves2half2(__float2half_rn(wx), __float2half_rn(wy));
        wxyr[t] = pk.ui;
        wzr[t] = wz;

        float a00 = redux16(wx * dx);
        float a01 = redux16(wx * dy);
        float a02 = redux16(wx * dz);
        float a11 = redux16(wy * dy);
        float a12 = redux16(wy * dz);
        float a22 = redux16(wz * dz);
        float b0  = redux16(wx * dv);
        float b1  = redux16(wy * dv);
        float b2  = redux16(wz * dv);

        if (act && lane == 0) {
            double A00 = (double)a00 + EPS_A;
            double A11 = (double)a11 + EPS_A;
            double A22 = (double)a22 + EPS_A;
            double A01 = (double)a01, A02 = (double)a02, A12 = (double)a12;
            double j00 = A11 * A22 - A12 * A12;
            double j01 = A02 * A12 - A01 * A22;
            double j02 = A01 * A12 - A02 * A11;
            double j11 = A00 * A22 - A02 * A02;
            double j12 = A01 * A02 - A00 * A12;
            double j22 = A00 * A11 - A01 * A01;
            double det = A00 * j00 + A01 * j01 + A02 * j02;
            double inv = 1.0 / det;
            float m00 = (float)(j00 * inv), m01 = (float)(j01 * inv);
            float m02 = (float)(j02 * inv), m11 = (float)(j11 * inv);
            float m12 = (float)(j12 * inv), m22 = (float)(j22 * inv);
            G[node] = make_float4(m00 * b0 + m01 * b1 + m02 * b2,
                                  m01 * b0 + m11 * b1 + m12 * b2,
                                  m02 * b0 + m12 * b1 + m22 * b2, 0.0f);
            sM[local][0] = m00; sM[local][1] = m01; sM[local][2] = m02;
            sM[local][3] = m11; sM[local][4] = m12; sM[local][5] = m22;
        }
    }
    cg::this_grid().sync();

    // phase 2: Hessian; only memory op is the G gather
    #pragma unroll
    for (int t = 0; t < ITER; ++t) {
        const int local = t * GRP + sub;
        const int node  = nbase + local;
        const bool act  = (local < NPB) && (node < N_NODES);

        union { __half2 h2; unsigned int ui; } pk;
        pk.ui = wxyr[t];
        float wx = __low2float(pk.h2);
        float wy = __high2float(pk.h2);
        float wz = wzr[t];

        float dv0 = 0.f, dv1 = 0.f, dv2 = 0.f;
        if (act) {
            float4 gi = G[node];
            float4 gj = G[idxr[t]];
            dv0 = gj.x - gi.x; dv1 = gj.y - gi.y; dv2 = gj.z - gi.z;
        }

        float b00 = redux16(wx * dv0);
        float b10 = redux16(wy * dv0);
        float b20 = redux16(wz * dv0);
        float b01 = redux16(wx * dv1);
        float b11 = redux16(wy * dv1);
        float b21 = redux16(wz * dv1);
        float b02 = redux16(wx * dv2);
        float b12 = redux16(wy * dv2);
        float b22 = redux16(wz * dv2);

        if (act && lane == 0) {
            float m00 = sM[local][0], m01 = sM[local][1], m02 = sM[local][2];
            float m11 = sM[local][3], m12 = sM[local][4], m22 = sM[local][5];
            float x00 = m00 * b00 + m01 * b10 + m02 * b20;
            float x10 = m01 * b00 + m11 * b10 + m12 * b20;
            float x20 = m02 * b00 + m12 * b10 + m22 * b20;
            float x11 = m01 * b01 + m11 * b11 + m12 * b21;
            float x21 = m02 * b01 + m12 * b11 + m22 * b21;
            float x22 = m02 * b02 + m12 * b12 + m22 * b22;
            f32x2* o2 = (f32x2*)(out + 6 * node);
            f32x2 o0 = {x00, x11};
            f32x2 o1 = {x22, x10};
            f32x2 o2v = {x20, x21};
            __builtin_nontemporal_store(o0,  o2 + 0);
            __builtin_nontemporal_store(o1,  o2 + 1);
            __builtin_nontemporal_store(o2v, o2 + 2);
        }
    }
}

// ==================== FALLBACK: R4 3-kernel path ====================

__global__ __launch_bounds__(256) void pack_p1(
    const float* __restrict__ coords,
    const float* __restrict__ u,
    float4* __restrict__ p1)
{
    int i = blockIdx.x * 256 + threadIdx.x;
    if (i >= N_NODES) return;
    p1[i] = make_float4(coords[3 * i], coords[3 * i + 1],
                        coords[3 * i + 2], u[i]);
}

__global__ __launch_bounds__(256) void lsq_pass1_x(
    const float4* __restrict__ p1,
    const int*    __restrict__ indices,
    float4*       __restrict__ G,
    f32x4*        __restrict__ M,
    f32x2*        __restrict__ WDX)
{
    int tid  = blockIdx.x * 256 + threadIdx.x;
    int node = tid >> 4;
    int lane = tid & 15;
    if (node >= N_NODES) return;

    float4 c = p1[node];
    int e = node * DEG + lane;
    int j = __builtin_nontemporal_load(indices + e);
    float4 p = p1[j];

    float dx = p.x - c.x, dy = p.y - c.y, dz = p.z - c.z, dv = p.w - c.w;
    float w = 1.0f / fmaxf(dx * dx + dy * dy + dz * dz, EPS_W);
    float wx = w * dx, wy = w * dy, wz = w * dz;

    union { __half h[4]; f32x2 f2; } pk;
    pk.h[0] = __float2half_rn(wx);
    pk.h[1] = __float2half_rn(wy);
    pk.h[2] = __float2half_rn(wz);
    pk.h[3] = __float2half_rn(0.0f);
    __builtin_nontemporal_store(pk.f2, WDX + e);

    float a00 = redux16(wx * dx);
    float a01 = redux16(wx * dy);
    float a02 = redux16(wx * dz);
    float a11 = redux16(wy * dy);
    float a12 = redux16(wy * dz);
    float a22 = redux16(wz * dz);
    float b0  = redux16(wx * dv);
    float b1  = redux16(wy * dv);
    float b2  = redux16(wz * dv);

    if (lane == 0) {
        double A00 = (double)a00 + EPS_A;
        double A11 = (double)a11 + EPS_A;
        double A22 = (double)a22 + EPS_A;
        double A01 = (double)a01, A02 = (double)a02, A12 = (double)a12;
        double j00 = A11 * A22 - A12 * A12;
        double j01 = A02 * A12 - A01 * A22;
        double j02 = A01 * A12 - A02 * A11;
        double j11 = A00 * A22 - A02 * A02;
        double j12 = A01 * A02 - A00 * A12;
        double j22 = A00 * A11 - A01 * A01;
        double det = A00 * j00 + A01 * j01 + A02 * j02;
        double inv = 1.0 / det;
        float m00 = (float)(j00 * inv), m01 = (float)(j01 * inv);
        float m02 = (float)(j02 * inv), m11 = (float)(j11 * inv);
        float m12 = (float)(j12 * inv), m22 = (float)(j22 * inv);
        G[node] = make_float4(m00 * b0 + m01 * b1 + m02 * b2,
                              m01 * b0 + m11 * b1 + m12 * b2,
                              m02 * b0 + m12 * b1 + m22 * b2, 0.0f);
        f32x4 mv0 = {m00, m01, m02, m11};
        f32x4 mv1 = {m12, m22, 0.0f, 0.0f};
        __builtin_nontemporal_store(mv0, M + 2 * node);
        __builtin_nontemporal_store(mv1, M + 2 * node + 1);
    }
}

__global__ __launch_bounds__(256) void lsq_pass2_x(
    const float4* __restrict__ G,
    const f32x4*  __restrict__ M,
    const f32x2*  __restrict__ WDX,
    const int*    __restrict__ indices,
    float*        __restrict__ out)
{
    int tid  = blockIdx.x * 256 + threadIdx.x;
    int node = tid >> 4;
    int lane = tid & 15;
    if (node >= N_NODES) return;

    float4 gi = G[node];
    int e = node * DEG + lane;
    int j = __builtin_nontemporal_load(indices + e);
    union { __half h[4]; f32x2 f2; } pk;
    pk.f2 = __builtin_nontemporal_load(WDX + e);
    float wx = __half2float(pk.h[0]);
    float wy = __half2float(pk.h[1]);
    float wz = __half2float(pk.h[2]);

    float4 gj = G[j];
    float dv0 = gj.x - gi.x, dv1 = gj.y - gi.y, dv2 = gj.z - gi.z;

    float b00 = redux16(wx * dv0);
    float b10 = redux16(wy * dv0);
    float b20 = redux16(wz * dv0);
    float b01 = redux16(wx * dv1);
    float b11 = redux16(wy * dv1);
    float b21 = redux16(wz * dv1);
    float b02 = redux16(wx * dv2);
    float b12 = redux16(wy * dv2);
    float b22 = redux16(wz * dv2);

    if (lane == 0) {
        f32x4 m0 = __builtin_nontemporal_load(M + 2 * node);
        f32x4 m1 = __builtin_nontemporal_load(M + 2 * node + 1);
        float m00 = m0.x, m01 = m0.y, m02 = m0.z, m11 = m0.w;
        float m12 = m1.x, m22 = m1.y;
        float x00 = m00 * b00 + m01 * b10 + m02 * b20;
        float x10 = m01 * b00 + m11 * b10 + m12 * b20;
        float x20 = m02 * b00 + m12 * b10 + m22 * b20;
        float x11 = m01 * b01 + m11 * b11 + m12 * b21;
        float x21 = m02 * b01 + m12 * b11 + m22 * b21;
        float x22 = m02 * b02 + m12 * b12 + m22 * b22;
        f32x2* o2 = (f32x2*)(out + 6 * node);
        f32x2 o0 = {x00, x11};
        f32x2 o1 = {x22, x10};
        f32x2 o2v = {x20, x21};
        __builtin_nontemporal_store(o0,  o2 + 0);
        __builtin_nontemporal_store(o1,  o2 + 1);
        __builtin_nontemporal_store(o2v, o2 + 2);
    }
}

extern "C" void kernel_launch(void* const* d_in, const int* in_sizes, int n_in,
                              void* d_out, int out_size, void* d_ws, size_t ws_size,
                              hipStream_t stream) {
    const float* coords  = (const float*)d_in[0];
    const float* u       = (const float*)d_in[1];
    const int*   indices = (const int*)d_in[3];
    float*       out     = (float*)d_out;

    char* ws = (char*)d_ws;
    const size_t szP1 = (size_t)N_NODES * 16;            // 4.8 MB
    const size_t szG  = (size_t)N_NODES * 16;            // 4.8 MB
    float4* P1 = (float4*)ws;
    float4* G  = (float4*)(ws + szP1);

    // --- try the fused cooperative kernel first ---
    const float* c_ = coords; const float* u_ = u; const int* i_ = indices;
    float4* p1_ = P1; float4* g_ = G; float* o_ = out;
    void* kargs[] = { (void*)&c_, (void*)&u_, (void*)&i_,
                      (void*)&p1_, (void*)&g_, (void*)&o_ };
    hipError_t err = hipLaunchCooperativeKernel((void*)lsq_fused, dim3(NBLK),
                                                dim3(TPB), kargs, 0, stream);
    if (err == hipSuccess) return;

    // --- deterministic fallback: R4 3-kernel path ---
    const int block = 256;
    const int grid_edges = (N_NODES * DEG) / block;
    const int grid_nodes = (N_NODES + block - 1) / block;

    f32x4* M   = (f32x4*)(ws + szP1 + szG);              // 9.6 MB
    f32x2* WDX = (f32x2*)(ws + szP1 + szG + (size_t)N_NODES * 32); // 38.4 MB

    pack_p1<<<grid_nodes, block, 0, stream>>>(coords, u, P1);
    lsq_pass1_x<<<grid_edges, block, 0, stream>>>(P1, indices, G, M, WDX);
    lsq_pass2_x<<<grid_edges, block, 0, stream>>>(G, M, WDX, indices, out);
}

// Round 7
// 151.212 us; speedup vs baseline: 2.8734x; 2.8734x over previous
//
#include <hip/hip_runtime.h>
#include <hip/hip_fp16.h>

// GradientsLeastSquares — R7: back to the proven R4 3-kernel structure
// (R6 showed wall-minus-kernel overhead is ~constant ~65-80us regardless of
// launch count, so fusion buys nothing; coop version also spilled 56MB to
// scratch). Both passes are bound by requests*latency/outstanding, so:
//   - 4 edges/thread (4 lanes per node): int4 index loads, 4 independent
//     gathers in flight per thread, 2-step quad reduction (half the shuffles).
//   - WDX split into SoA planes: wxy(half2, 4B/edge) + wz(f16, 2B/edge)
//     = 28.8MB round-trip (was 38.4) with ideal coalescing.
//   - streams NT; gather arrays (P1, G) cached.
//
// ws layout: P1 float4[N] @0 (4.8MB) | G float4[N] (4.8MB) | M f32x4[2N]
//            (9.6MB) | WXY u32[E] (19.2MB) | WZ f16[E] (9.6MB)  = 48MB.

constexpr int N_NODES = 300000;
constexpr int DEG = 16;
constexpr float EPS_W = 1e-12f;
constexpr double EPS_A = 1e-8;

typedef float        f32x4 __attribute__((ext_vector_type(4)));
typedef float        f32x2 __attribute__((ext_vector_type(2)));
typedef int          i32x4 __attribute__((ext_vector_type(4)));
typedef unsigned int u32x4 __attribute__((ext_vector_type(4)));
typedef unsigned int u32x2 __attribute__((ext_vector_type(2)));

__device__ __forceinline__ float redux4(float v) {
    v += __shfl_xor(v, 1, 4);
    v += __shfl_xor(v, 2, 4);
    return v;
}

__device__ __forceinline__ unsigned int pack_h2(float a, float b) {
    union { __half2 h2; unsigned int ui; } pk;
    pk.h2 = __halves2half2(__float2half_rn(a), __float2half_rn(b));
    return pk.ui;
}

// ---------------- Pack: P1[i] = {cx,cy,cz,u} ----------------
__global__ __launch_bounds__(256) void pack_p1(
    const float* __restrict__ coords,
    const float* __restrict__ u,
    float4* __restrict__ p1)
{
    int i = blockIdx.x * 256 + threadIdx.x;
    if (i >= N_NODES) return;
    p1[i] = make_float4(coords[3 * i], coords[3 * i + 1],
                        coords[3 * i + 2], u[i]);
}

// ---------------- Pass 1: scalar gradient; exports WXY/WZ/M ----------------
__global__ __launch_bounds__(256) void lsq_pass1(
    const float4*  __restrict__ P,
    const int*     __restrict__ indices,
    float4*        __restrict__ G,
    f32x4*         __restrict__ M,
    unsigned int*  __restrict__ WXY,   // half2{wx,wy} per edge
    unsigned int*  __restrict__ WZ)    // 2x f16 wz per u32
{
    int tid  = blockIdx.x * 256 + threadIdx.x;
    int node = tid >> 2;
    int q    = tid & 3;
    if (node >= N_NODES) return;

    float4 c = P[node];
    int ebase = node * DEG + q * 4;
    i32x4 idx = __builtin_nontemporal_load((const i32x4*)(indices + ebase));

    // issue all 4 gathers before consuming (independent, 4x MLP)
    float4 n0 = P[idx.x];
    float4 n1 = P[idx.y];
    float4 n2 = P[idx.z];
    float4 n3 = P[idx.w];

    float a00 = 0, a01 = 0, a02 = 0, a11 = 0, a12 = 0, a22 = 0;
    float b0 = 0, b1 = 0, b2 = 0;
    float wxs[4], wys[4], wzs[4];
    float4 nb[4] = {n0, n1, n2, n3};
    #pragma unroll
    for (int k = 0; k < 4; ++k) {
        float dx = nb[k].x - c.x, dy = nb[k].y - c.y;
        float dz = nb[k].z - c.z, dv = nb[k].w - c.w;
        float w = 1.0f / fmaxf(dx * dx + dy * dy + dz * dz, EPS_W);
        float wx = w * dx, wy = w * dy, wz = w * dz;
        wxs[k] = wx; wys[k] = wy; wzs[k] = wz;
        a00 += wx * dx; a01 += wx * dy; a02 += wx * dz;
        a11 += wy * dy; a12 += wy * dz; a22 += wz * dz;
        b0 += wx * dv; b1 += wy * dv; b2 += wz * dv;
    }

    // export per-edge weighted directions (SoA, NT, ideally coalesced)
    u32x4 wxy = { pack_h2(wxs[0], wys[0]), pack_h2(wxs[1], wys[1]),
                  pack_h2(wxs[2], wys[2]), pack_h2(wxs[3], wys[3]) };
    __builtin_nontemporal_store(wxy, (u32x4*)(WXY + ebase));
    u32x2 wzp = { pack_h2(wzs[0], wzs[1]), pack_h2(wzs[2], wzs[3]) };
    __builtin_nontemporal_store(wzp, (u32x2*)(WZ + (ebase >> 1)));

    a00 = redux4(a00); a01 = redux4(a01); a02 = redux4(a02);
    a11 = redux4(a11); a12 = redux4(a12); a22 = redux4(a22);
    b0 = redux4(b0); b1 = redux4(b1); b2 = redux4(b2);

    if (q == 0) {
        double A00 = (double)a00 + EPS_A;
        double A11 = (double)a11 + EPS_A;
        double A22 = (double)a22 + EPS_A;
        double A01 = (double)a01, A02 = (double)a02, A12 = (double)a12;
        double j00 = A11 * A22 - A12 * A12;
        double j01 = A02 * A12 - A01 * A22;
        double j02 = A01 * A12 - A02 * A11;
        double j11 = A00 * A22 - A02 * A02;
        double j12 = A01 * A02 - A00 * A12;
        double j22 = A00 * A11 - A01 * A01;
        double det = A00 * j00 + A01 * j01 + A02 * j02;
        double inv = 1.0 / det;
        float m00 = (float)(j00 * inv), m01 = (float)(j01 * inv);
        float m02 = (float)(j02 * inv), m11 = (float)(j11 * inv);
        float m12 = (float)(j12 * inv), m22 = (float)(j22 * inv);
        G[node] = make_float4(m00 * b0 + m01 * b1 + m02 * b2,
                              m01 * b0 + m11 * b1 + m12 * b2,
                              m02 * b0 + m12 * b1 + m22 * b2, 0.0f);
        f32x4 mv0 = {m00, m01, m02, m11};
        f32x4 mv1 = {m12, m22, 0.0f, 0.0f};
        __builtin_nontemporal_store(mv0, M + 2 * node);
        __builtin_nontemporal_store(mv1, M + 2 * node + 1);
    }
}

// ---------------- Pass 2: Hessian; only gather is G ----------------
__global__ __launch_bounds__(256) void lsq_pass2(
    const float4*       __restrict__ G,
    const f32x4*        __restrict__ M,
    const unsigned int* __restrict__ WXY,
    const unsigned int* __restrict__ WZ,
    const int*          __restrict__ indices,
    float*              __restrict__ out)   // [N,6]: xx,yy,zz,xy,xz,yz
{
    int tid  = blockIdx.x * 256 + threadIdx.x;
    int node = tid >> 2;
    int q    = tid & 3;
    if (node >= N_NODES) return;

    float4 gi = G[node];
    int ebase = node * DEG + q * 4;
    i32x4 idx = __builtin_nontemporal_load((const i32x4*)(indices + ebase));
    u32x4 wxy = __builtin_nontemporal_load((const u32x4*)(WXY + ebase));
    u32x2 wzp = __builtin_nontemporal_load((const u32x2*)(WZ + (ebase >> 1)));

    // 4 independent gathers in flight
    float4 g0 = G[idx.x];
    float4 g1 = G[idx.y];
    float4 g2 = G[idx.z];
    float4 g3 = G[idx.w];

    float b00 = 0, b10 = 0, b20 = 0;
    float b01 = 0, b11 = 0, b21 = 0;
    float b02 = 0, b12 = 0, b22 = 0;
    float4 gb[4] = {g0, g1, g2, g3};
    unsigned int wzs[2] = {wzp.x, wzp.y};
    unsigned int wxys[4] = {wxy.x, wxy.y, wxy.z, wxy.w};
    #pragma unroll
    for (int k = 0; k < 4; ++k) {
        union { __half2 h2; unsigned int ui; } pk;
        pk.ui = wxys[k];
        float wx = __low2float(pk.h2);
        float wy = __high2float(pk.h2);
        union { __half2 h2; unsigned int ui; } pz;
        pz.ui = wzs[k >> 1];
        float wz = (k & 1) ? __high2float(pz.h2) : __low2float(pz.h2);
        float dv0 = gb[k].x - gi.x, dv1 = gb[k].y - gi.y, dv2 = gb[k].z - gi.z;
        b00 += wx * dv0; b10 += wy * dv0; b20 += wz * dv0;
        b01 += wx * dv1; b11 += wy * dv1; b21 += wz * dv1;
        b02 += wx * dv2; b12 += wy * dv2; b22 += wz * dv2;
    }

    b00 = redux4(b00); b10 = redux4(b10); b20 = redux4(b20);
    b01 = redux4(b01); b11 = redux4(b11); b21 = redux4(b21);
    b02 = redux4(b02); b12 = redux4(b12); b22 = redux4(b22);

    if (q == 0) {
        f32x4 m0 = __builtin_nontemporal_load(M + 2 * node);
        f32x4 m1 = __builtin_nontemporal_load(M + 2 * node + 1);
        float m00 = m0.x, m01 = m0.y, m02 = m0.z, m11 = m0.w;
        float m12 = m1.x, m22 = m1.y;
        float x00 = m00 * b00 + m01 * b10 + m02 * b20; // xx
        float x10 = m01 * b00 + m11 * b10 + m12 * b20; // xy
        float x20 = m02 * b00 + m12 * b10 + m22 * b20; // xz
        float x11 = m01 * b01 + m11 * b11 + m12 * b21; // yy
        float x21 = m02 * b01 + m12 * b11 + m22 * b21; // yz
        float x22 = m02 * b02 + m12 * b12 + m22 * b22; // zz
        f32x2* o2 = (f32x2*)(out + 6 * node);
        f32x2 o0 = {x00, x11};
        f32x2 o1 = {x22, x10};
        f32x2 o2v = {x20, x21};
        __builtin_nontemporal_store(o0,  o2 + 0);
        __builtin_nontemporal_store(o1,  o2 + 1);
        __builtin_nontemporal_store(o2v, o2 + 2);
    }
}

extern "C" void kernel_launch(void* const* d_in, const int* in_sizes, int n_in,
                              void* d_out, int out_size, void* d_ws, size_t ws_size,
                              hipStream_t stream) {
    const float* coords  = (const float*)d_in[0];
    const float* u       = (const float*)d_in[1];
    const int*   indices = (const int*)d_in[3];
    float*       out     = (float*)d_out;

    char* ws = (char*)d_ws;
    const size_t szP1  = (size_t)N_NODES * 16;           // 4.8 MB
    const size_t szG   = (size_t)N_NODES * 16;           // 4.8 MB
    const size_t szM   = (size_t)N_NODES * 32;           // 9.6 MB
    const size_t szWXY = (size_t)N_NODES * DEG * 4;      // 19.2 MB

    float4*       P1  = (float4*)ws;
    float4*       G   = (float4*)(ws + szP1);
    f32x4*        M   = (f32x4*)(ws + szP1 + szG);
    unsigned int* WXY = (unsigned int*)(ws + szP1 + szG + szM);
    unsigned int* WZ  = (unsigned int*)(ws + szP1 + szG + szM + szWXY);

    const int block = 256;
    const int grid_nodes = (N_NODES + block - 1) / block;
    const int threads4 = N_NODES * 4;                    // 1.2M
    const int grid4 = (threads4 + block - 1) / block;    // 4688

    pack_p1<<<grid_nodes, block, 0, stream>>>(coords, u, P1);
    lsq_pass1<<<grid4, block, 0, stream>>>(P1, indices, G, M, WXY, WZ);
    lsq_pass2<<<grid4, block, 0, stream>>>(G, M, WXY, WZ, indices, out);
}

// Round 8
// 144.687 us; speedup vs baseline: 3.0030x; 1.0451x over previous
//
#include <hip/hip_runtime.h>
#include <hip/hip_fp16.h>

// GradientsLeastSquares — R8 = R7 + f16-packed G (8 B/node).
// R2's measured law: gather fetch ≈ E·64B·(1−C/S), C = 4.19 MB per-XCD L2.
// R7's pass2 gathered float4 G (S=4.8MB, ~13% miss). f16×4 G → S=2.4MB,
// fully L2-resident per XCD → pass2's only HBM traffic is streams.
// f16 g error (5e-4 rel) enters dv symmetrically with the already-f16 wdx
// (absmax 0.25 observed) → expect ~0.5, threshold 16.24.
//
// ws: P1 float4[N] 4.8MB | Gh u32x2[N] 2.4MB | M f32x4[2N] 9.6MB |
//     WXY u32[E] 19.2MB | WZ u32[E/2] 9.6MB   = 45.6MB

constexpr int N_NODES = 300000;
constexpr int DEG = 16;
constexpr float EPS_W = 1e-12f;
constexpr double EPS_A = 1e-8;

typedef float        f32x4 __attribute__((ext_vector_type(4)));
typedef float        f32x2 __attribute__((ext_vector_type(2)));
typedef int          i32x4 __attribute__((ext_vector_type(4)));
typedef unsigned int u32x4 __attribute__((ext_vector_type(4)));
typedef unsigned int u32x2 __attribute__((ext_vector_type(2)));

__device__ __forceinline__ float redux4(float v) {
    v += __shfl_xor(v, 1, 4);
    v += __shfl_xor(v, 2, 4);
    return v;
}

__device__ __forceinline__ unsigned int pack_h2(float a, float b) {
    union { __half2 h2; unsigned int ui; } pk;
    pk.h2 = __halves2half2(__float2half_rn(a), __float2half_rn(b));
    return pk.ui;
}

__device__ __forceinline__ f32x2 unpack_h2(unsigned int v) {
    union { __half2 h2; unsigned int ui; } pk;
    pk.ui = v;
    f32x2 r = { __low2float(pk.h2), __high2float(pk.h2) };
    return r;
}

// ---------------- Pack: P1[i] = {cx,cy,cz,u} ----------------
__global__ __launch_bounds__(256) void pack_p1(
    const float* __restrict__ coords,
    const float* __restrict__ u,
    float4* __restrict__ p1)
{
    int i = blockIdx.x * 256 + threadIdx.x;
    if (i >= N_NODES) return;
    p1[i] = make_float4(coords[3 * i], coords[3 * i + 1],
                        coords[3 * i + 2], u[i]);
}

// ---------------- Pass 1: scalar gradient; exports Gh/WXY/WZ/M ----------------
__global__ __launch_bounds__(256) void lsq_pass1(
    const float4*  __restrict__ P,
    const int*     __restrict__ indices,
    u32x2*         __restrict__ Gh,    // f16 {g0,g1,g2,0} per node
    f32x4*         __restrict__ M,
    unsigned int*  __restrict__ WXY,   // half2{wx,wy} per edge
    unsigned int*  __restrict__ WZ)    // 2x f16 wz per u32
{
    int tid  = blockIdx.x * 256 + threadIdx.x;
    int node = tid >> 2;
    int q    = tid & 3;
    if (node >= N_NODES) return;

    float4 c = P[node];
    int ebase = node * DEG + q * 4;
    i32x4 idx = __builtin_nontemporal_load((const i32x4*)(indices + ebase));

    float4 n0 = P[idx.x];
    float4 n1 = P[idx.y];
    float4 n2 = P[idx.z];
    float4 n3 = P[idx.w];

    float a00 = 0, a01 = 0, a02 = 0, a11 = 0, a12 = 0, a22 = 0;
    float b0 = 0, b1 = 0, b2 = 0;
    float wxs[4], wys[4], wzs[4];
    float4 nb[4] = {n0, n1, n2, n3};
    #pragma unroll
    for (int k = 0; k < 4; ++k) {
        float dx = nb[k].x - c.x, dy = nb[k].y - c.y;
        float dz = nb[k].z - c.z, dv = nb[k].w - c.w;
        float w = 1.0f / fmaxf(dx * dx + dy * dy + dz * dz, EPS_W);
        float wx = w * dx, wy = w * dy, wz = w * dz;
        wxs[k] = wx; wys[k] = wy; wzs[k] = wz;
        a00 += wx * dx; a01 += wx * dy; a02 += wx * dz;
        a11 += wy * dy; a12 += wy * dz; a22 += wz * dz;
        b0 += wx * dv; b1 += wy * dv; b2 += wz * dv;
    }

    u32x4 wxy = { pack_h2(wxs[0], wys[0]), pack_h2(wxs[1], wys[1]),
                  pack_h2(wxs[2], wys[2]), pack_h2(wxs[3], wys[3]) };
    __builtin_nontemporal_store(wxy, (u32x4*)(WXY + ebase));
    u32x2 wzp = { pack_h2(wzs[0], wzs[1]), pack_h2(wzs[2], wzs[3]) };
    __builtin_nontemporal_store(wzp, (u32x2*)(WZ + (ebase >> 1)));

    a00 = redux4(a00); a01 = redux4(a01); a02 = redux4(a02);
    a11 = redux4(a11); a12 = redux4(a12); a22 = redux4(a22);
    b0 = redux4(b0); b1 = redux4(b1); b2 = redux4(b2);

    if (q == 0) {
        double A00 = (double)a00 + EPS_A;
        double A11 = (double)a11 + EPS_A;
        double A22 = (double)a22 + EPS_A;
        double A01 = (double)a01, A02 = (double)a02, A12 = (double)a12;
        double j00 = A11 * A22 - A12 * A12;
        double j01 = A02 * A12 - A01 * A22;
        double j02 = A01 * A12 - A02 * A11;
        double j11 = A00 * A22 - A02 * A02;
        double j12 = A01 * A02 - A00 * A12;
        double j22 = A00 * A11 - A01 * A01;
        double det = A00 * j00 + A01 * j01 + A02 * j02;
        double inv = 1.0 / det;
        float m00 = (float)(j00 * inv), m01 = (float)(j01 * inv);
        float m02 = (float)(j02 * inv), m11 = (float)(j11 * inv);
        float m12 = (float)(j12 * inv), m22 = (float)(j22 * inv);
        float g0 = m00 * b0 + m01 * b1 + m02 * b2;
        float g1 = m01 * b0 + m11 * b1 + m12 * b2;
        float g2 = m02 * b0 + m12 * b1 + m22 * b2;
        u32x2 gp = { pack_h2(g0, g1), pack_h2(g2, 0.0f) };
        Gh[node] = gp;                       // cached (gather target in pass2)
        f32x4 mv0 = {m00, m01, m02, m11};
        f32x4 mv1 = {m12, m22, 0.0f, 0.0f};
        __builtin_nontemporal_store(mv0, M + 2 * node);
        __builtin_nontemporal_store(mv1, M + 2 * node + 1);
    }
}

// ---------------- Pass 2: Hessian; gather set = 2.4 MB (L2-resident) ----------
__global__ __launch_bounds__(256) void lsq_pass2(
    const u32x2*        __restrict__ Gh,
    const f32x4*        __restrict__ M,
    const unsigned int* __restrict__ WXY,
    const unsigned int* __restrict__ WZ,
    const int*          __restrict__ indices,
    float*              __restrict__ out)   // [N,6]: xx,yy,zz,xy,xz,yz
{
    int tid  = blockIdx.x * 256 + threadIdx.x;
    int node = tid >> 2;
    int q    = tid & 3;
    if (node >= N_NODES) return;

    u32x2 gip = Gh[node];
    f32x2 gi01 = unpack_h2(gip.x);
    f32x2 gi2_ = unpack_h2(gip.y);
    float gi0 = gi01.x, gi1 = gi01.y, gi2 = gi2_.x;

    int ebase = node * DEG + q * 4;
    i32x4 idx = __builtin_nontemporal_load((const i32x4*)(indices + ebase));
    u32x4 wxy = __builtin_nontemporal_load((const u32x4*)(WXY + ebase));
    u32x2 wzp = __builtin_nontemporal_load((const u32x2*)(WZ + (ebase >> 1)));

    // 4 independent gathers in flight, all L2 hits (2.4 MB set)
    u32x2 gp0 = Gh[idx.x];
    u32x2 gp1 = Gh[idx.y];
    u32x2 gp2 = Gh[idx.z];
    u32x2 gp3 = Gh[idx.w];

    float b00 = 0, b10 = 0, b20 = 0;
    float b01 = 0, b11 = 0, b21 = 0;
    float b02 = 0, b12 = 0, b22 = 0;
    u32x2 gb[4] = {gp0, gp1, gp2, gp3};
    unsigned int wzs[2] = {wzp.x, wzp.y};
    unsigned int wxys[4] = {wxy.x, wxy.y, wxy.z, wxy.w};
    #pragma unroll
    for (int k = 0; k < 4; ++k) {
        f32x2 wxyf = unpack_h2(wxys[k]);
        float wx = wxyf.x, wy = wxyf.y;
        f32x2 wzf = unpack_h2(wzs[k >> 1]);
        float wz = (k & 1) ? wzf.y : wzf.x;
        f32x2 gj01 = unpack_h2(gb[k].x);
        f32x2 gj2_ = unpack_h2(gb[k].y);
        float dv0 = gj01.x - gi0, dv1 = gj01.y - gi1, dv2 = gj2_.x - gi2;
        b00 += wx * dv0; b10 += wy * dv0; b20 += wz * dv0;
        b01 += wx * dv1; b11 += wy * dv1; b21 += wz * dv1;
        b02 += wx * dv2; b12 += wy * dv2; b22 += wz * dv2;
    }

    b00 = redux4(b00); b10 = redux4(b10); b20 = redux4(b20);
    b01 = redux4(b01); b11 = redux4(b11); b21 = redux4(b21);
    b02 = redux4(b02); b12 = redux4(b12); b22 = redux4(b22);

    if (q == 0) {
        f32x4 m0 = __builtin_nontemporal_load(M + 2 * node);
        f32x4 m1 = __builtin_nontemporal_load(M + 2 * node + 1);
        float m00 = m0.x, m01 = m0.y, m02 = m0.z, m11 = m0.w;
        float m12 = m1.x, m22 = m1.y;
        float x00 = m00 * b00 + m01 * b10 + m02 * b20; // xx
        float x10 = m01 * b00 + m11 * b10 + m12 * b20; // xy
        float x20 = m02 * b00 + m12 * b10 + m22 * b20; // xz
        float x11 = m01 * b01 + m11 * b11 + m12 * b21; // yy
        float x21 = m02 * b01 + m12 * b11 + m22 * b21; // yz
        float x22 = m02 * b02 + m12 * b12 + m22 * b22; // zz
        f32x2* o2 = (f32x2*)(out + 6 * node);
        f32x2 o0 = {x00, x11};
        f32x2 o1 = {x22, x10};
        f32x2 o2v = {x20, x21};
        __builtin_nontemporal_store(o0,  o2 + 0);
        __builtin_nontemporal_store(o1,  o2 + 1);
        __builtin_nontemporal_store(o2v, o2 + 2);
    }
}

extern "C" void kernel_launch(void* const* d_in, const int* in_sizes, int n_in,
                              void* d_out, int out_size, void* d_ws, size_t ws_size,
                              hipStream_t stream) {
    const float* coords  = (const float*)d_in[0];
    const float* u       = (const float*)d_in[1];
    const int*   indices = (const int*)d_in[3];
    float*       out     = (float*)d_out;

    char* ws = (char*)d_ws;
    const size_t szP1  = (size_t)N_NODES * 16;           // 4.8 MB
    const size_t szGh  = (size_t)N_NODES * 8;            // 2.4 MB
    const size_t szM   = (size_t)N_NODES * 32;           // 9.6 MB
    const size_t szWXY = (size_t)N_NODES * DEG * 4;      // 19.2 MB

    float4*       P1  = (float4*)ws;
    u32x2*        Gh  = (u32x2*)(ws + szP1);
    f32x4*        M   = (f32x4*)(ws + szP1 + szGh);
    unsigned int* WXY = (unsigned int*)(ws + szP1 + szGh + szM);
    unsigned int* WZ  = (unsigned int*)(ws + szP1 + szGh + szM + szWXY);

    const int block = 256;
    const int grid_nodes = (N_NODES + block - 1) / block;
    const int threads4 = N_NODES * 4;                    // 1.2M
    const int grid4 = (threads4 + block - 1) / block;    // 4688

    pack_p1<<<grid_nodes, block, 0, stream>>>(coords, u, P1);
    lsq_pass1<<<grid4, block, 0, stream>>>(P1, indices, Gh, M, WXY, WZ);
    lsq_pass2<<<grid4, block, 0, stream>>>(Gh, M, WXY, WZ, indices, out);
}